// Round 1
// baseline (4716.771 us; speedup 1.0000x reference)
//
#include <hip/hip_runtime.h>
#include <hip/hip_bf16.h>
#include <hip/hip_fp16.h>

#define T_ 512
#define B_ 128
#define E_ 256
#define H_ 256
#define NW 16   // workgroups per direction in the recurrence kernel

typedef _Float16 h8 __attribute__((ext_vector_type(8)));
typedef float    f4 __attribute__((ext_vector_type(4)));

// ---------------------------------------------------------------------------
// K1: embedding gather + fp32->fp16, written in MFMA A-fragment order:
// frag(t, mt, kb) element addr = ((t*64 + mt*8 + kb)*64 + lane)*8 halves,
// holding x[t][b = mt*16 + (lane&15)][e = kb*32 + (lane>>4)*8 + j], j=0..7
// ---------------------------------------------------------------------------
__global__ __launch_bounds__(256) void k_gather(const int* __restrict__ tok,
        const float* __restrict__ emb, _Float16* __restrict__ x16)
{
    const int t = blockIdx.x;
    const int tid = threadIdx.x;
    const int wave = tid >> 6, lane = tid & 63;
    const int q = lane >> 4, l16 = lane & 15;
    __shared__ int rows[B_];
    if (tid < B_) rows[tid] = tok[(size_t)tid * T_ + t];
    __syncthreads();
    for (int it = 0; it < 16; ++it) {
        int pair = it * 4 + wave;          // pair = mt*8 + kb
        int mt = pair >> 3, kb = pair & 7;
        int b = mt * 16 + l16;
        int e = kb * 32 + q * 8;
        const float* src = emb + (size_t)rows[b] * E_ + e;
        float4 a = *(const float4*)src;
        float4 c = *(const float4*)(src + 4);
        h8 hv;
        hv[0]=(_Float16)a.x; hv[1]=(_Float16)a.y; hv[2]=(_Float16)a.z; hv[3]=(_Float16)a.w;
        hv[4]=(_Float16)c.x; hv[5]=(_Float16)c.y; hv[6]=(_Float16)c.z; hv[7]=(_Float16)c.w;
        *(h8*)(x16 + (((size_t)t * 64 + pair) * 64 + lane) * 8) = hv;
    }
}

// ---------------------------------------------------------------------------
// K2: weight permute+convert. Output Wp[d][w][n][k]: n in [0,64) = gate*16+jl,
// k in [0,512): k<256 -> W[k][col], k>=256 -> U[k-256][col], col = g*256+w*16+jl.
// fp16, n-major so K3's per-lane 16B B-fragment loads are contiguous in k.
// ---------------------------------------------------------------------------
__global__ __launch_bounds__(256) void k_wperm(const float* __restrict__ Wf, const float* __restrict__ Uf,
        const float* __restrict__ Wb, const float* __restrict__ Ub, _Float16* __restrict__ wp)
{
    const int wg = blockIdx.x;           // 0..31
    const int d = wg >> 4, w = wg & 15;
    const int tid = threadIdx.x;
    const float* W = d ? Wb : Wf;
    const float* U = d ? Ub : Uf;
    __shared__ _Float16 S[256][66];      // padded to break bank alignment
    _Float16* out = wp + (size_t)wg * 64 * 512;
    for (int half = 0; half < 2; ++half) {
        const float* src = half ? U : W;
        for (int it = 0; it < 64; ++it) {
            int idx = it * 256 + tid;
            int k = idx >> 6, n = idx & 63;
            int g = n >> 4, jl = n & 15;
            int col = g * 256 + w * 16 + jl;
            S[k][n] = (_Float16)src[(size_t)k * 1024 + col];
        }
        __syncthreads();
        for (int it = 0; it < 64; ++it) {
            int idx = it * 256 + tid;
            int n = idx >> 8, k = idx & 255;
            out[n * 512 + half * 256 + k] = S[k][n];
        }
        __syncthreads();
    }
}

// ---------------------------------------------------------------------------
// K3: persistent bidirectional LSTM recurrence. 32 blocks (16 per direction),
// 256 threads. WG w owns hidden units j = w*16 .. w*16+15 (64 gate columns).
// Weights [512 x 64] fp16 resident in VGPRs. Per-direction flag barrier each
// step; H broadcast through a double-buffered global fp16 buffer.
// ---------------------------------------------------------------------------
__device__ __forceinline__ float fsig(float x) {
    float t = __expf(-fabsf(x));
    float r = __builtin_amdgcn_rcpf(1.0f + t);
    return x >= 0.f ? r : 1.0f - r;
}
__device__ __forceinline__ float ftanh(float x) {
    float t = __expf(-2.0f * fabsf(x));
    float r = (1.0f - t) * __builtin_amdgcn_rcpf(1.0f + t);
    return x >= 0.f ? r : -r;
}

__global__ __launch_bounds__(256, 1) void k_rnn(const _Float16* __restrict__ x16,
        const _Float16* __restrict__ wp, const float* __restrict__ bf, const float* __restrict__ bb,
        _Float16* __restrict__ hbuf, float* __restrict__ hfin, unsigned int* __restrict__ flags)
{
    const int wg = blockIdx.x;
    const int d = wg >> 4, w = wg & 15;
    const int tid = threadIdx.x;
    const int wave = tid >> 6, lane = tid & 63;
    const int q = lane >> 4, l16 = lane & 15;

    // persistent weight fragments: wx = x-part (k 0..255), wu = h-part (k 256..511)
    h8 wx[4][8], wu[4][8];
    {
        const h8* base = (const h8*)(wp + (size_t)wg * 64 * 512);
        #pragma unroll
        for (int nt = 0; nt < 4; ++nt)
            #pragma unroll
            for (int kb = 0; kb < 8; ++kb) {
                wx[nt][kb] = base[(nt * 16 + l16) * 64 + kb * 4 + q];
                wu[nt][kb] = base[(nt * 16 + l16) * 64 + (kb + 8) * 4 + q];
            }
    }
    const float* bias = d ? bb : bf;
    const float bs0 = bias[0 * 256 + w * 16 + l16];
    const float bs1 = bias[1 * 256 + w * 16 + l16];
    const float bs2 = bias[2 * 256 + w * 16 + l16];
    const float bs3 = bias[3 * 256 + w * 16 + l16];

    unsigned int* myflags = flags + d * 32;

    float c[2][4];
    #pragma unroll
    for (int mt = 0; mt < 2; ++mt)
        #pragma unroll
        for (int r = 0; r < 4; ++r) c[mt][r] = 0.f;

    // prefetch x fragments for step 0
    h8 xf[2][8];
    {
        int xt = d ? (T_ - 1) : 0;
        const h8* xb = (const h8*)x16 + ((size_t)xt * 64 + (size_t)(wave * 2) * 8) * 64 + lane;
        #pragma unroll
        for (int mt = 0; mt < 2; ++mt)
            #pragma unroll
            for (int kb = 0; kb < 8; ++kb)
                xf[mt][kb] = xb[(mt * 8 + kb) * 64];
    }

    f4 acc[2][4];

    for (int s = 0; s < T_; ++s) {
        if (s > 0) {
            // wait for all 16 WGs of this direction to publish h_s
            if (tid < NW) {
                while (__hip_atomic_load(&myflags[tid], __ATOMIC_RELAXED, __HIP_MEMORY_SCOPE_AGENT) < (unsigned)s)
                    __builtin_amdgcn_s_sleep(1);
            }
            __syncthreads();
            __builtin_amdgcn_fence(__ATOMIC_ACQUIRE, "agent");
            // H fragments, direct from global (LLC)
            h8 hf[2][8];
            {
                const h8* hb = (const h8*)(hbuf + (size_t)((s & 1) * 2 + d) * B_ * H_);
                #pragma unroll
                for (int mt = 0; mt < 2; ++mt) {
                    int b = (wave * 2 + mt) * 16 + l16;
                    #pragma unroll
                    for (int kb = 0; kb < 8; ++kb)
                        hf[mt][kb] = hb[b * 32 + kb * 4 + q];
                }
            }
            // x-part (fragments were prefetched last iteration; overlaps hf latency)
            #pragma unroll
            for (int mt = 0; mt < 2; ++mt)
                #pragma unroll
                for (int nt = 0; nt < 4; ++nt) {
                    f4 a = {0.f, 0.f, 0.f, 0.f};
                    #pragma unroll
                    for (int kb = 0; kb < 8; ++kb)
                        a = __builtin_amdgcn_mfma_f32_16x16x32_f16(xf[mt][kb], wx[nt][kb], a, 0, 0, 0);
                    acc[mt][nt] = a;
                }
            // h-part
            #pragma unroll
            for (int kb = 0; kb < 8; ++kb)
                #pragma unroll
                for (int mt = 0; mt < 2; ++mt)
                    #pragma unroll
                    for (int nt = 0; nt < 4; ++nt)
                        acc[mt][nt] = __builtin_amdgcn_mfma_f32_16x16x32_f16(hf[mt][kb], wu[nt][kb], acc[mt][nt], 0, 0, 0);
        } else {
            #pragma unroll
            for (int mt = 0; mt < 2; ++mt)
                #pragma unroll
                for (int nt = 0; nt < 4; ++nt) {
                    f4 a = {0.f, 0.f, 0.f, 0.f};
                    #pragma unroll
                    for (int kb = 0; kb < 8; ++kb)
                        a = __builtin_amdgcn_mfma_f32_16x16x32_f16(xf[mt][kb], wx[nt][kb], a, 0, 0, 0);
                    acc[mt][nt] = a;
                }
        }
        // gates (fp32), update c, emit h
        {
            _Float16* hout = hbuf + (size_t)(((s + 1) & 1) * 2 + d) * B_ * H_;
            #pragma unroll
            for (int mt = 0; mt < 2; ++mt)
                #pragma unroll
                for (int r = 0; r < 4; ++r) {
                    float zi = acc[mt][0][r] + bs0;
                    float zf = acc[mt][1][r] + bs1;
                    float zg = acc[mt][2][r] + bs2;
                    float zo = acc[mt][3][r] + bs3;
                    float cn = fsig(zf) * c[mt][r] + fsig(zi) * ftanh(zg);
                    c[mt][r] = cn;
                    float hh = fsig(zo) * ftanh(cn);
                    int b = (wave * 2 + mt) * 16 + q * 4 + r;
                    hout[b * H_ + w * 16 + l16] = (_Float16)hh;
                    if (s == T_ - 1)
                        hfin[((size_t)d * B_ + b) * H_ + w * 16 + l16] = hh;
                }
        }
        __builtin_amdgcn_fence(__ATOMIC_RELEASE, "agent");
        __syncthreads();
        if (tid == 0)
            __hip_atomic_store(&myflags[w], (unsigned)(s + 1), __ATOMIC_RELAXED, __HIP_MEMORY_SCOPE_AGENT);
        // prefetch next step's x fragments; in flight during the spin
        if (s < T_ - 1) {
            int xt = d ? (T_ - 2 - s) : (s + 1);
            const h8* xb = (const h8*)x16 + ((size_t)xt * 64 + (size_t)(wave * 2) * 8) * 64 + lane;
            #pragma unroll
            for (int mt = 0; mt < 2; ++mt)
                #pragma unroll
                for (int kb = 0; kb < 8; ++kb)
                    xf[mt][kb] = xb[(mt * 8 + kb) * 64];
        }
    }
}

// ---------------------------------------------------------------------------
// K4: head. One block per batch row: a1 = relu([h_fwd|h_bwd] @ W1 + b1),
// logits = a1 @ W2 + b2, softmax over 32 classes. All fp32.
// ---------------------------------------------------------------------------
__global__ __launch_bounds__(256) void k_head(const float* __restrict__ hfin,
        const float* __restrict__ W1, const float* __restrict__ b1,
        const float* __restrict__ W2, const float* __restrict__ b2, float* __restrict__ out)
{
    const int b = blockIdx.x;
    const int tid = threadIdx.x;
    __shared__ float hcat[2 * H_];
    __shared__ float a1[256];
    if (tid < 128) {
        if (tid < 64)
            ((float4*)hcat)[tid] = ((const float4*)(hfin + (size_t)b * H_))[tid];
        else
            ((float4*)(hcat + H_))[tid - 64] = ((const float4*)(hfin + (size_t)(B_ + b) * H_))[tid - 64];
    }
    __syncthreads();
    {
        float s = b1[tid];
        #pragma unroll 4
        for (int k = 0; k < 2 * H_; ++k)
            s += hcat[k] * W1[(size_t)k * 256 + tid];
        a1[tid] = s > 0.f ? s : 0.f;
    }
    __syncthreads();
    if (tid < 32) {
        float s = b2[tid];
        #pragma unroll 4
        for (int j = 0; j < 256; ++j)
            s += a1[j] * W2[(size_t)j * 32 + tid];
        float mx = s;
        #pragma unroll
        for (int o = 16; o > 0; o >>= 1)
            mx = fmaxf(mx, __shfl_xor(mx, o, 32));
        float e = __expf(s - mx);
        float sum = e;
        #pragma unroll
        for (int o = 16; o > 0; o >>= 1)
            sum += __shfl_xor(sum, o, 32);
        out[(size_t)b * 32 + tid] = e / sum;
    }
}

// ---------------------------------------------------------------------------
extern "C" void kernel_launch(void* const* d_in, const int* in_sizes, int n_in,
                              void* d_out, int out_size, void* d_ws, size_t ws_size,
                              hipStream_t stream)
{
    (void)in_sizes; (void)n_in; (void)out_size; (void)ws_size;
    const int*   tok = (const int*)d_in[0];
    const float* emb = (const float*)d_in[1];
    const float* Wf  = (const float*)d_in[2];
    const float* Uf  = (const float*)d_in[3];
    const float* bf  = (const float*)d_in[4];
    const float* Wb  = (const float*)d_in[5];
    const float* Ub  = (const float*)d_in[6];
    const float* bb  = (const float*)d_in[7];
    const float* W1  = (const float*)d_in[8];
    const float* b1  = (const float*)d_in[9];
    const float* W2  = (const float*)d_in[10];
    const float* b2  = (const float*)d_in[11];
    float* out = (float*)d_out;

    char* ws = (char*)d_ws;
    _Float16* x16   = (_Float16*)(ws);                 // 33,554,432 B  frag-ordered x
    _Float16* wp    = (_Float16*)(ws + 33554432);      //  2,097,152 B  permuted weights
    _Float16* hbuf  = (_Float16*)(ws + 35651584);      //    262,144 B  H double buffer [2][2][128][256]
    float*    hfin  = (float*)   (ws + 35913728);      //    262,144 B  final h fp32 [2][128][256]
    unsigned* flags = (unsigned*)(ws + 36175872);      //        512 B  barrier flags

    hipMemsetAsync(flags, 0, 512, stream);
    k_gather<<<T_, 256, 0, stream>>>(tok, emb, x16);
    k_wperm <<<32,  256, 0, stream>>>(Wf, Uf, Wb, Ub, wp);
    k_rnn   <<<32,  256, 0, stream>>>(x16, wp, bf, bb, hbuf, hfin, flags);
    k_head  <<<B_,  256, 0, stream>>>(hfin, W1, b1, W2, b2, out);
}